// Round 2
// baseline (134.076 us; speedup 1.0000x reference)
//
#include <hip/hip_runtime.h>

#define NH 8
#define NF 16
#define NNODE 1024
#define INF 200
#define OUTF 128

// ---------------- Kernel 1: g_l = x @ W_l, g_r = x @ W_r (all f32) ----------
// x: [1024, 200] f32, W: [200, 128] f32, g: [1024, 128] f32
// One block per (16-row tile, l/r). x-tile staged in LDS (reads are wave-
// broadcast: all 64 lanes of a wave share r0, so xs reads hit one bank,
// broadcast). W streamed from global: per k-step threads 0..127 read a
// coalesced 512B line, threads 128..255 hit L1 on the same line.
__global__ __launch_bounds__(256) void proj_kernel(
        const float* __restrict__ x,
        const float* __restrict__ Wl,
        const float* __restrict__ Wr,
        float* __restrict__ gl,
        float* __restrict__ gr) {
    __shared__ float xs[16 * INF];      // 12800 B
    const float* __restrict__ W = blockIdx.y ? Wr : Wl;
    float* __restrict__ g = blockIdx.y ? gr : gl;
    const int i0 = blockIdx.x * 16;
    const int tid = threadIdx.x;

    {   // stage x tile: 3200 floats = 800 float4
        const float4* src = (const float4*)(x + i0 * INF);
        float4* dst = (float4*)xs;
        for (int t = tid; t < (16 * INF) / 4; t += 256) dst[t] = src[t];
    }
    __syncthreads();

    const int c = tid & 127;            // output column 0..127
    const int r0 = (tid >> 7) * 8;      // rows r0..r0+7
    float acc[8] = {0.f, 0.f, 0.f, 0.f, 0.f, 0.f, 0.f, 0.f};
    for (int k = 0; k < INF; ++k) {
        const float w = W[k * OUTF + c];
#pragma unroll
        for (int r = 0; r < 8; ++r)
            acc[r] = fmaf(xs[(r0 + r) * INF + k], w, acc[r]);
    }
#pragma unroll
    for (int r = 0; r < 8; ++r)
        g[(i0 + r0 + r) * OUTF + c] = acc[r];
}

// ---------------- Kernel 2: fused scores + masked softmax + PV --------------
// One block per node i. 512 threads = 8 waves; wave w owns head w in
// phases B (softmax) and C (PV).
__global__ __launch_bounds__(512) void gat_fused(
        const float* __restrict__ gl,
        const float* __restrict__ gr,
        const int* __restrict__ adj,
        const float* __restrict__ attn_w,
        float* __restrict__ out) {
    constexpr int ES = 1028;            // padded row stride
    __shared__ float es[NH * ES];       // 32896 B: e, then p, per head
    __shared__ float gri[OUTF];         // g_r row i

    const int i = blockIdx.x;
    const int tid = threadIdx.x;
    const int lane = tid & 63;
    const int wave = tid >> 6;

    if (tid < OUTF) gri[tid] = gr[i * OUTF + tid];
    __syncthreads();

    // ---- Phase A: e[i, j, h] for all (j, h). Thread owns h = tid&7,
    // j = (tid>>3) + 64*p. Groups of 8 threads (same j, h=0..7) together
    // read one contiguous 512B g_l row — fully coalesced.
    {
        const int h = tid & 7;
        const int jb = tid >> 3;        // 0..63
        float w[NF], grh[NF];
#pragma unroll
        for (int f = 0; f < NF; ++f) {
            w[f] = attn_w[f];
            grh[f] = gri[h * NF + f];
        }
        for (int p = 0; p < 16; ++p) {
            const int j = jb + p * 64;
            const float4* src = (const float4*)(gl + j * OUTF + h * NF);
            float4 v0 = src[0], v1 = src[1], v2 = src[2], v3 = src[3];
            float glv[NF] = {v0.x, v0.y, v0.z, v0.w,
                             v1.x, v1.y, v1.z, v1.w,
                             v2.x, v2.y, v2.z, v2.w,
                             v3.x, v3.y, v3.z, v3.w};
            float e = 0.f;
#pragma unroll
            for (int f = 0; f < NF; ++f) {
                float v = grh[f] + glv[f];
                v = fmaxf(v, 0.2f * v);     // leaky relu (slope < 1)
                e = fmaf(v, w[f], e);
            }
            const int m = adj[i * NNODE + j];
            es[h * ES + j] = m ? e : -INFINITY;
        }
    }
    __syncthreads();

    // ---- Phase B: masked softmax over j; wave handles head h = wave.
    {
        const int h = wave;
        float v[16];
        float m = -INFINITY;
#pragma unroll
        for (int k = 0; k < 16; ++k) {
            v[k] = es[h * ES + lane + k * 64];
            m = fmaxf(m, v[k]);
        }
#pragma unroll
        for (int d = 1; d < 64; d <<= 1) m = fmaxf(m, __shfl_xor(m, d, 64));
        float s = 0.f;
        float ex[16];
#pragma unroll
        for (int k = 0; k < 16; ++k) {
            ex[k] = __expf(v[k] - m);       // exp(-inf) = 0 for masked
            s += ex[k];
        }
#pragma unroll
        for (int d = 1; d < 64; d <<= 1) s += __shfl_xor(s, d, 64);
        const float inv = 1.f / s;
#pragma unroll
        for (int k = 0; k < 16; ++k) es[h * ES + lane + k * 64] = ex[k] * inv;
    }
    // no cross-wave dependency (wave h wrote and reads only head h), but the
    // barrier is once per block and keeps the phases clean.
    __syncthreads();

    // ---- Phase C: out[i, h, f] = sum_j p[j] * g_r[j, h, f]; wave = head h.
    // lane = jg*4 + c4: c4 covers f-quad, jg covers 16 j-groups of 64.
    {
        const int h = wave;
        const int c4 = lane & 3;
        const int jg = lane >> 2;
        float4 acc = {0.f, 0.f, 0.f, 0.f};
        for (int t = 0; t < 64; ++t) {
            const int j = jg * 64 + ((t + jg) & 63);   // stagger: 16 distinct banks
            const float p = es[h * ES + j];
            const float4 v = *(const float4*)(gr + j * OUTF + h * NF + c4 * 4);
            acc.x = fmaf(p, v.x, acc.x);
            acc.y = fmaf(p, v.y, acc.y);
            acc.z = fmaf(p, v.z, acc.z);
            acc.w = fmaf(p, v.w, acc.w);
        }
#pragma unroll
        for (int d = 4; d < 64; d <<= 1) {
            acc.x += __shfl_xor(acc.x, d, 64);
            acc.y += __shfl_xor(acc.y, d, 64);
            acc.z += __shfl_xor(acc.z, d, 64);
            acc.w += __shfl_xor(acc.w, d, 64);
        }
        if (lane < 4)
            *(float4*)(out + i * OUTF + h * NF + c4 * 4) = acc;
    }
}

extern "C" void kernel_launch(void* const* d_in, const int* in_sizes, int n_in,
                              void* d_out, int out_size, void* d_ws, size_t ws_size,
                              hipStream_t stream) {
    const float* h   = (const float*)d_in[0];   // [1,1024,200] f32
    const int*   adj = (const int*)d_in[1];     // [1,1024,1024] int32
    const float* Wl  = (const float*)d_in[2];   // [200,128] f32
    const float* Wr  = (const float*)d_in[3];   // [200,128] f32
    const float* aw  = (const float*)d_in[4];   // [16] f32
    float* out = (float*)d_out;                 // [1,1024,128] f32

    float* gl = (float*)d_ws;                   // [1024,128] f32
    float* gr = gl + NNODE * OUTF;              // [1024,128] f32

    proj_kernel<<<dim3(64, 2), 256, 0, stream>>>(h, Wl, Wr, gl, gr);
    gat_fused<<<dim3(NNODE), 512, 0, stream>>>(gl, gr, adj, aw, out);
}

// Round 3
// 106.622 us; speedup vs baseline: 1.2575x; 1.2575x over previous
//
#include <hip/hip_runtime.h>

#define NH 8
#define NF 16
#define NNODE 1024
#define INF 200
#define OUTF 128
#define TI 2            // nodes per block in the fused kernel
#define ES 1028         // padded row stride (breaks pow2 banks)

// ---------------- Kernel 1: g_l = x @ W_l, g_r = x @ W_r (all f32) ----------
// 256 blocks (8-row tiles x {l,r}), 256 threads: c = tid&127, 4 rows/thread.
__global__ __launch_bounds__(256) void proj_kernel(
        const float* __restrict__ x,
        const float* __restrict__ Wl,
        const float* __restrict__ Wr,
        float* __restrict__ gl,
        float* __restrict__ gr) {
    __shared__ float xs[8 * INF];       // 6400 B
    const float* __restrict__ W = blockIdx.y ? Wr : Wl;
    float* __restrict__ g = blockIdx.y ? gr : gl;
    const int i0 = blockIdx.x * 8;
    const int tid = threadIdx.x;

    {   // stage x tile: 1600 floats = 400 float4
        const float4* src = (const float4*)(x + i0 * INF);
        float4* dst = (float4*)xs;
        for (int t = tid; t < (8 * INF) / 4; t += 256) dst[t] = src[t];
    }
    __syncthreads();

    const int c = tid & 127;            // output column
    const int r0 = (tid >> 7) * 4;      // rows r0..r0+3
    float acc[4] = {0.f, 0.f, 0.f, 0.f};
#pragma unroll 4
    for (int k = 0; k < INF; ++k) {
        const float w = W[k * OUTF + c];
#pragma unroll
        for (int r = 0; r < 4; ++r)
            acc[r] = fmaf(xs[(r0 + r) * INF + k], w, acc[r]);
    }
#pragma unroll
    for (int r = 0; r < 4; ++r)
        g[(i0 + r0 + r) * OUTF + c] = acc[r];
}

// ---------------- Kernel 2: fused scores + masked softmax + PV --------------
// One block per TI=2 nodes. 512 threads = 8 waves; wave w = head w in
// phases B/C. Every gl row (phase A) and gr row (phase C) load is reused
// for both nodes -> halves L2 traffic vs 1-node blocks.
__global__ __launch_bounds__(512) void gat_fused(
        const float* __restrict__ gl,
        const float* __restrict__ gr,
        const int* __restrict__ adj,
        const float* __restrict__ attn_w,
        float* __restrict__ out) {
    __shared__ float es[TI * NH * ES];  // 65792 B: e, then p, per (node, head)
    __shared__ float gri[TI * OUTF];    // g_r rows i0, i0+1

    const int i0 = blockIdx.x * TI;
    const int tid = threadIdx.x;
    const int lane = tid & 63;
    const int wave = tid >> 6;

    if (tid < TI * OUTF) gri[tid] = gr[i0 * OUTF + tid];
    __syncthreads();

    // ---- Phase A: e[i, j, h] for i in {i0, i0+1}, all (j, h).
    // Thread owns h = tid&7, j = (tid>>3) + 64*p. Groups of 8 threads
    // (same j, h=0..7) read one contiguous 512B g_l row — fully coalesced,
    // and the row feeds BOTH nodes' scores.
    {
        const int h = tid & 7;
        const int jb = tid >> 3;        // 0..63
        float w[NF], g0[NF], g1[NF];
#pragma unroll
        for (int f = 0; f < NF; ++f) {
            w[f] = attn_w[f];
            g0[f] = gri[h * NF + f];
            g1[f] = gri[OUTF + h * NF + f];
        }
        const int* __restrict__ adj0 = adj + i0 * NNODE;
        const int* __restrict__ adj1 = adj0 + NNODE;
#pragma unroll 4
        for (int p = 0; p < 16; ++p) {
            const int j = jb + p * 64;
            const float4* src = (const float4*)(gl + j * OUTF + h * NF);
            float4 v0 = src[0], v1 = src[1], v2 = src[2], v3 = src[3];
            const int m0 = adj0[j];
            const int m1 = adj1[j];
            float glv[NF] = {v0.x, v0.y, v0.z, v0.w,
                             v1.x, v1.y, v1.z, v1.w,
                             v2.x, v2.y, v2.z, v2.w,
                             v3.x, v3.y, v3.z, v3.w};
            float e0 = 0.f, e1 = 0.f;
#pragma unroll
            for (int f = 0; f < NF; ++f) {
                const float gv = glv[f];
                float a0 = g0[f] + gv;
                a0 = fmaxf(a0, 0.2f * a0);          // leaky relu (slope<1)
                e0 = fmaf(a0, w[f], e0);
                float a1 = g1[f] + gv;
                a1 = fmaxf(a1, 0.2f * a1);
                e1 = fmaf(a1, w[f], e1);
            }
            es[h * ES + j] = m0 ? e0 : -INFINITY;
            es[(NH + h) * ES + j] = m1 ? e1 : -INFINITY;
        }
    }
    __syncthreads();

    // ---- Phase B: masked softmax over j; wave w = head w, both nodes.
    {
        const int h = wave;
#pragma unroll
        for (int il = 0; il < TI; ++il) {
            const int base = (il * NH + h) * ES;
            float v[16];
            float m = -INFINITY;
#pragma unroll
            for (int k = 0; k < 16; ++k) {
                v[k] = es[base + lane + k * 64];
                m = fmaxf(m, v[k]);
            }
#pragma unroll
            for (int d = 1; d < 64; d <<= 1) m = fmaxf(m, __shfl_xor(m, d, 64));
            float s = 0.f;
            float ex[16];
#pragma unroll
            for (int k = 0; k < 16; ++k) {
                ex[k] = __expf(v[k] - m);           // exp(-inf)=0 for masked
                s += ex[k];
            }
#pragma unroll
            for (int d = 1; d < 64; d <<= 1) s += __shfl_xor(s, d, 64);
            const float inv = 1.f / s;
#pragma unroll
            for (int k = 0; k < 16; ++k) es[base + lane + k * 64] = ex[k] * inv;
        }
    }
    __syncthreads();

    // ---- Phase C: out[i, h, f] = sum_j p[j] * g_r[j, h, f]; wave = head h.
    // lane = jg*4 + c4; each gr float4 load feeds BOTH nodes.
    {
        const int h = wave;
        const int c4 = lane & 3;
        const int jg = lane >> 2;
        const int b0 = h * ES;
        const int b1 = (NH + h) * ES;
        float4 a0 = {0.f, 0.f, 0.f, 0.f};
        float4 a1 = {0.f, 0.f, 0.f, 0.f};
#pragma unroll 4
        for (int t = 0; t < 64; ++t) {
            const int j = jg * 64 + ((t + jg) & 63);   // stagger: distinct banks
            const float p0 = es[b0 + j];
            const float p1 = es[b1 + j];
            const float4 v = *(const float4*)(gr + j * OUTF + h * NF + c4 * 4);
            a0.x = fmaf(p0, v.x, a0.x);
            a0.y = fmaf(p0, v.y, a0.y);
            a0.z = fmaf(p0, v.z, a0.z);
            a0.w = fmaf(p0, v.w, a0.w);
            a1.x = fmaf(p1, v.x, a1.x);
            a1.y = fmaf(p1, v.y, a1.y);
            a1.z = fmaf(p1, v.z, a1.z);
            a1.w = fmaf(p1, v.w, a1.w);
        }
#pragma unroll
        for (int d = 4; d < 64; d <<= 1) {
            a0.x += __shfl_xor(a0.x, d, 64);
            a0.y += __shfl_xor(a0.y, d, 64);
            a0.z += __shfl_xor(a0.z, d, 64);
            a0.w += __shfl_xor(a0.w, d, 64);
            a1.x += __shfl_xor(a1.x, d, 64);
            a1.y += __shfl_xor(a1.y, d, 64);
            a1.z += __shfl_xor(a1.z, d, 64);
            a1.w += __shfl_xor(a1.w, d, 64);
        }
        if (lane < 4) {
            *(float4*)(out + i0 * OUTF + h * NF + c4 * 4) = a0;
            *(float4*)(out + (i0 + 1) * OUTF + h * NF + c4 * 4) = a1;
        }
    }
}

extern "C" void kernel_launch(void* const* d_in, const int* in_sizes, int n_in,
                              void* d_out, int out_size, void* d_ws, size_t ws_size,
                              hipStream_t stream) {
    const float* h   = (const float*)d_in[0];   // [1,1024,200] f32
    const int*   adj = (const int*)d_in[1];     // [1,1024,1024] int32
    const float* Wl  = (const float*)d_in[2];   // [200,128] f32
    const float* Wr  = (const float*)d_in[3];   // [200,128] f32
    const float* aw  = (const float*)d_in[4];   // [16] f32
    float* out = (float*)d_out;                 // [1,1024,128] f32

    float* gl = (float*)d_ws;                   // [1024,128] f32
    float* gr = gl + NNODE * OUTF;              // [1024,128] f32

    proj_kernel<<<dim3(128, 2), 256, 0, stream>>>(h, Wl, Wr, gl, gr);
    gat_fused<<<dim3(NNODE / TI), 512, 0, stream>>>(gl, gr, adj, aw, out);
}